// Round 6
// baseline (2502.779 us; speedup 1.0000x reference)
//
#include <hip/hip_runtime.h>
#include <cmath>

typedef unsigned long long u64;
typedef unsigned int u32;
typedef unsigned char u8;

#define SCAN_BLOCK 256
#define SCAN_ELEMS 8
#define SCAN_TILE (SCAN_BLOCK * SCAN_ELEMS)

// coarse bins for the edge scatter: 512 vertices per bin.
// record packing (mn&511)<<18 | mx requires V <= 2^18 (here V=200000). 
#define BIN_SHIFT 9
#define BIN_VR 512
#define BIN_CAP 16384   // avg load ~7.7K at these sizes; 16K is >30 sigma

__constant__ int d_NUMTRI[16] = {0,1,1,2,1,2,2,1,1,2,2,1,2,1,1,0};
__constant__ int d_TRI[16][6] = {
 {-1,-1,-1,-1,-1,-1},{1,0,2,-1,-1,-1},{4,0,3,-1,-1,-1},{1,4,2,1,3,4},
 {3,1,5,-1,-1,-1},{2,3,0,2,5,3},{1,4,0,1,5,4},{4,2,5,-1,-1,-1},
 {4,5,2,-1,-1,-1},{4,1,0,4,5,1},{3,2,0,3,5,2},{1,3,5,-1,-1,-1},
 {4,1,2,4,3,1},{3,0,4,-1,-1,-1},{2,0,1,-1,-1,-1},{-1,-1,-1,-1,-1,-1}};
__constant__ int d_E0[6] = {0,0,0,1,1,2};
__constant__ int d_E1[6] = {1,2,3,2,3,3};

// ---------------- exclusive scan, templated element type ----------------
// NOTE: tet m1/m2 scan MUST be u64 — running m1 total needs 19 bits packed at
// bit 21 (overflowed u32 in round 3).
template <typename T>
__global__ void scanA_t(const T* in, T* out, int n, T* blockSums) {
    __shared__ T tsum[SCAN_BLOCK];
    int tbase = blockIdx.x * SCAN_TILE + threadIdx.x * SCAN_ELEMS;
    T vals[SCAN_ELEMS];
    T run = 0;
    for (int k = 0; k < SCAN_ELEMS; ++k) {
        int i = tbase + k;
        T v = (i < n) ? in[i] : (T)0;
        vals[k] = run;
        run += v;
    }
    tsum[threadIdx.x] = run;
    __syncthreads();
    for (int off = 1; off < SCAN_BLOCK; off <<= 1) {
        T v = (threadIdx.x >= (unsigned)off) ? tsum[threadIdx.x - off] : (T)0;
        __syncthreads();
        tsum[threadIdx.x] += v;
        __syncthreads();
    }
    T texcl = (threadIdx.x == 0) ? (T)0 : tsum[threadIdx.x - 1];
    for (int k = 0; k < SCAN_ELEMS; ++k) {
        int i = tbase + k;
        if (i < n) out[i] = texcl + vals[k];
    }
    if (threadIdx.x == SCAN_BLOCK - 1) blockSums[blockIdx.x] = tsum[SCAN_BLOCK - 1];
}

template <typename T>
__global__ void scanB_t(T* bs, int nb, T* totalOut) {
    __shared__ T sh[2048];
    for (int i = threadIdx.x; i < 2048; i += 256) sh[i] = (i < nb) ? bs[i] : (T)0;
    __syncthreads();
    for (int off = 1; off < 2048; off <<= 1) {
        T v[8];
        for (int k = 0; k < 8; ++k) {
            int i = threadIdx.x + k * 256;
            v[k] = (i >= off) ? sh[i - off] : (T)0;
        }
        __syncthreads();
        for (int k = 0; k < 8; ++k) sh[threadIdx.x + k * 256] += v[k];
        __syncthreads();
    }
    for (int i = threadIdx.x; i < nb; i += 256) bs[i] = (i == 0) ? (T)0 : sh[i - 1];
    if (threadIdx.x == 0 && totalOut) *totalOut = (nb > 0) ? sh[nb - 1] : (T)0;
}

template <typename T>
__global__ void scanC_t(T* out, int n, const T* bs) {
    int base = blockIdx.x * SCAN_TILE;
    T add = bs[blockIdx.x];
    int end = base + SCAN_TILE; if (end > n) end = n;
    for (int i = base + threadIdx.x; i < end; i += SCAN_BLOCK) out[i] += add;
}

// ---------------- pipeline ----------------
// classify + push crossing edges into coarse bins (u32 records, L2-local writes)
__global__ void k_classify_bin(const int* tet, const float* sdf, u8* ti8, u64* tetPack,
                               u32* binCursor, u32* binData, int T) {
    int t = blockIdx.x * 256 + threadIdx.x;
    if (t >= T) return;
    int4 q = reinterpret_cast<const int4*>(tet)[t];
    int ti = (sdf[q.x] > 0.0f ? 1 : 0) | (sdf[q.y] > 0.0f ? 2 : 0) |
             (sdf[q.z] > 0.0f ? 4 : 0) | (sdf[q.w] > 0.0f ? 8 : 0);
    ti8[t] = (u8)ti;
    int nt = d_NUMTRI[ti];
    tetPack[t] = ((u64)(nt == 1 ? 1 : 0) << 21) | (u64)(nt == 2 ? 1 : 0);
    if (nt == 0) return;
    int idx[4] = {q.x, q.y, q.z, q.w};
    #pragma unroll
    for (int e = 0; e < 6; ++e) {
        int e0 = d_E0[e], e1 = d_E1[e];
        if (((ti >> e0) ^ (ti >> e1)) & 1) {
            int a = idx[e0], b = idx[e1];
            int mn = a < b ? a : b;
            int mx = a < b ? b : a;
            int bin = mn >> BIN_SHIFT;
            u32 slot = atomicAdd(&binCursor[bin], 1u);
            if (slot < BIN_CAP)
                binData[(size_t)bin * BIN_CAP + slot] =
                    ((u32)(mn & (BIN_VR - 1)) << 18) | (u32)mx;
        }
    }
}

// one block per bin: LDS histogram -> coalesced bucketCnt write (no global atomics)
__global__ __launch_bounds__(256) void k_bincount(
    const u32* binCursor, const u32* binData, u32* bucketCnt, int V) {
    int bin = blockIdx.x;
    __shared__ u32 hist[BIN_VR];
    for (int i = threadIdx.x; i < BIN_VR; i += 256) hist[i] = 0;
    __syncthreads();
    int n = (int)binCursor[bin];
    if (n > BIN_CAP) n = BIN_CAP;
    const u32* bd = binData + (size_t)bin * BIN_CAP;
    for (int i = threadIdx.x; i < n; i += 256) atomicAdd(&hist[bd[i] >> 18], 1u);
    __syncthreads();
    int vbase = bin << BIN_SHIFT;
    for (int i = threadIdx.x; i < BIN_VR; i += 256) {
        int v = vbase + i;
        if (v < V) bucketCnt[v] = hist[i];
    }
}

// round bucket counts up to 16 u32s => every bucket starts 64B-aligned
__global__ void k_pad(const u32* bucketCnt, u32* padCnt, int V) {
    int v = blockIdx.x * 256 + threadIdx.x;
    if (v < V) padCnt[v] = (bucketCnt[v] + 15u) & ~15u;
}

// one block per bin: LDS cursors (absolute) -> scatter mx into maxArr.
// writes land in a ~40KB window per bin -> L2-combined, writeback ~= payload.
__global__ __launch_bounds__(256) void k_binscatter(
    const u32* binCursor, const u32* binData, const u32* bucketStart,
    u32* maxArr, int V) {
    int bin = blockIdx.x;
    __shared__ u32 cur[BIN_VR];
    int vbase = bin << BIN_SHIFT;
    for (int i = threadIdx.x; i < BIN_VR; i += 256) {
        int v = vbase + i;
        cur[i] = (v < V) ? bucketStart[v] : 0u;
    }
    __syncthreads();
    int n = (int)binCursor[bin];
    if (n > BIN_CAP) n = BIN_CAP;
    const u32* bd = binData + (size_t)bin * BIN_CAP;
    for (int i = threadIdx.x; i < n; i += 256) {
        u32 rec = bd[i];
        u32 slot = atomicAdd(&cur[rec >> 18], 1u);
        maxArr[slot] = rec & 0x3FFFFu;
    }
}

// one wave per bucket. n<=64: pure cross-lane (shfl rank + ds_permute scatter +
// ballot dedup), no LDS, no barriers. n<=256: LDS rank-sort. else serial.
__global__ __launch_bounds__(64) void k_sortdedup(
    const u32* bucketCnt, const u32* bucketStart, u32* maxArr, u32* crossCnt, int V)
{
    int v = blockIdx.x;
    if (v >= V) return;
    int lane = threadIdx.x;
    int n = (int)bucketCnt[v];
    if (n == 0) { if (lane == 0) crossCnt[v] = 0; return; }
    long long start = (long long)bucketStart[v];

    if (n <= 64) {
        u32 key = (lane < n) ? maxArr[start + lane] : 0xFFFFFFFFu;
        int rank = 0;
        #pragma unroll 16
        for (int j = 0; j < 64; ++j) {
            u32 kj = (u32)__shfl((int)key, j);
            rank += (kj < key || (kj == key && j < lane)) ? 1 : 0;
        }
        u32 sorted = (u32)__builtin_amdgcn_ds_permute(rank << 2, (int)key);
        u32 prev = (u32)__shfl((int)sorted, lane - 1);
        bool nf = (lane < n) && (lane == 0 || prev != sorted);
        u64 m = __ballot(nf);
        int idx = __popcll(m & ((1ull << lane) - 1ull));
        if (nf) maxArr[start + idx] = sorted;
        if (lane == 0) crossCnt[v] = (u32)__popcll(m);
    } else if (n <= 256) {
        __shared__ u32 sk[256];
        __shared__ u32 ss[256];
        int chunks = (n + 63) >> 6;
        u32 key[4];
        #pragma unroll
        for (int c = 0; c < 4; ++c) {
            if (c < chunks) {
                int i = (c << 6) + lane;
                key[c] = (i < n) ? maxArr[start + i] : 0xFFFFFFFFu;
                sk[(c << 6) + lane] = key[c];
            }
        }
        __syncthreads();
        int rank[4] = {0, 0, 0, 0};
        for (int j = 0; j < n; ++j) {
            u32 kj = sk[j];
            #pragma unroll
            for (int c = 0; c < 4; ++c) {
                if (c < chunks) {
                    int i = (c << 6) + lane;
                    rank[c] += (kj < key[c] || (kj == key[c] && j < i)) ? 1 : 0;
                }
            }
        }
        #pragma unroll
        for (int c = 0; c < 4; ++c) {
            if (c < chunks) { int i = (c << 6) + lane; if (i < n) ss[rank[c]] = key[c]; }
        }
        __syncthreads();
        int carryU = 0;
        for (int c = 0; c < chunks; ++c) {
            int i = (c << 6) + lane;
            bool valid = i < n;
            u32 k = ss[i < 256 ? i : 255];
            bool nf = valid && (i == 0 || ss[i - 1] != k);
            u64 mnf = __ballot(nf);
            u64 incl = (2ull << lane) - 1ull;
            int uIncl = carryU + __popcll(mnf & incl);
            if (nf) maxArr[start + uIncl - 1] = k;
            carryU += __popcll(mnf);
        }
        if (lane == 0) crossCnt[v] = (u32)carryU;
    } else if (lane == 0) {
        for (int i = 1; i < n; ++i) {
            u32 kk = maxArr[start + i];
            int j = i - 1;
            while (j >= 0 && maxArr[start + j] > kk) {
                maxArr[start + j + 1] = maxArr[start + j]; --j;
            }
            maxArr[start + j + 1] = kk;
        }
        int uc = 0; u32 prev = 0xFFFFFFFFu;
        for (int i = 0; i < n; ++i) {
            u32 k = maxArr[start + i];
            if (k != prev) { maxArr[start + uc] = k; ++uc; prev = k; }
        }
        crossCnt[v] = (u32)uc;
    }
}

// pack per-vertex lookup metadata: x=start, y=(u<<22)|crossScan  (1.6 MB total)
__global__ void k_metapack(const u32* bucketStart, const u32* crossCnt,
                           const u32* crossScan, uint2* meta2, int V) {
    int v = blockIdx.x * 256 + threadIdx.x;
    if (v < V) meta2[v] = make_uint2(bucketStart[v], (crossCnt[v] << 22) | crossScan[v]);
}

// one wave per bucket; lane i -> unique crossing edge i -> vertex crossScan[v]+i
__global__ __launch_bounds__(64) void k_verts(
    const u32* crossCnt, const u32* bucketStart, const u32* maxArr, const u32* crossScan,
    const float* pos, const float* sdf, float* out, int V)
{
    int v = blockIdx.x;
    if (v >= V) return;
    int lane = threadIdx.x;
    int u = (int)crossCnt[v];
    if (u == 0) return;
    long long start = (long long)bucketStart[v];
    int cBase = (int)crossScan[v];
    float s0 = sdf[v];
    float p0x = pos[3 * v], p0y = pos[3 * v + 1], p0z = pos[3 * v + 2];
    for (int i = lane; i < u; i += 64) {
        int b = (int)maxArr[start + i];
        long long k = cBase + i;
        float s1 = sdf[b];
        float d = s0 - s1;
        float w0 = -s1 / d, w1 = s0 / d;
        out[3 * k + 0] = p0x * w0 + pos[3 * b + 0] * w1;
        out[3 * k + 1] = p0y * w0 + pos[3 * b + 1] * w1;
        out[3 * k + 2] = p0z * w0 + pos[3 * b + 2] * w1;
    }
}

// faces + uv_idx; edge->vertex id via uint4 scan of 64B-aligned sorted bucket
__global__ void k_faces(const int* tet, const u8* ti8, const u64* tetScan,
                        const uint2* meta2, const u32* maxArr,
                        const u64* meta0, const u32* NePtr,
                        float* out, int T, int Ngrid, long long uvFloats)
{
    int t = blockIdx.x * 256 + threadIdx.x;
    if (t >= T) return;
    int ti = ti8[t];
    int nt = d_NUMTRI[ti];
    if (nt == 0) return;

    u64 tot = *meta0;
    int C1 = (int)((tot >> 21) & 0x1fffffull);
    int C2 = (int)(tot & 0x1fffffull);
    int Ne = (int)*NePtr;
    long long facesBase = 3LL * Ne;
    long long F = (long long)C1 + 2LL * C2;
    long long uvIdxBase = facesBase + 3LL * F + uvFloats;

    int4 q = reinterpret_cast<const int4*>(tet)[t];
    int idx[4] = {q.x, q.y, q.z, q.w};
    const int* row = d_TRI[ti];

    int emap[6];
    unsigned done = 0;
    float fv[6];
    #pragma unroll
    for (int j = 0; j < 6; ++j) {
        if (j >= 3 * nt) break;
        int e = row[j];
        if (!((done >> e) & 1)) {
            done |= 1u << e;
            int a = idx[d_E0[e]], b = idx[d_E1[e]];
            if (a > b) { int tmp = a; a = b; b = tmp; }
            uint2 m = meta2[a];
            int u = (int)(m.y >> 22);
            int base = (int)(m.y & 0x3FFFFFu);
            const uint4* bp = (const uint4*)(maxArr + m.x);  // 64B-aligned
            int cnt = 0;
            int nv = (u + 3) >> 2;
            for (int k4 = 0; k4 < nv; ++k4) {
                uint4 w = bp[k4];
                int b4 = k4 << 2;
                cnt += (b4 + 0 < u && (int)w.x < b) ? 1 : 0;
                cnt += (b4 + 1 < u && (int)w.y < b) ? 1 : 0;
                cnt += (b4 + 2 < u && (int)w.z < b) ? 1 : 0;
                cnt += (b4 + 3 < u && (int)w.w < b) ? 1 : 0;
            }
            emap[e] = base + cnt;
        }
        fv[j] = (float)emap[e];
    }

    u64 sc = tetScan[t];
    int r1 = (int)((sc >> 21) & 0x1fffffull);
    int r2 = (int)(sc & 0x1fffffull);
    int tet_idx = (t / Ngrid) * Ngrid + (t % Ngrid);

    if (nt == 1) {
        long long f = r1;
        out[facesBase + 3 * f + 0] = fv[0];
        out[facesBase + 3 * f + 1] = fv[1];
        out[facesBase + 3 * f + 2] = fv[2];
        out[uvIdxBase + 3 * f + 0] = (float)(4 * tet_idx);
        out[uvIdxBase + 3 * f + 1] = (float)(4 * tet_idx + 1);
        out[uvIdxBase + 3 * f + 2] = (float)(4 * tet_idx + 2);
    } else {
        long long f0 = (long long)C1 + 2LL * r2;
        out[facesBase + 3 * f0 + 0] = fv[0];
        out[facesBase + 3 * f0 + 1] = fv[1];
        out[facesBase + 3 * f0 + 2] = fv[2];
        out[facesBase + 3 * (f0 + 1) + 0] = fv[3];
        out[facesBase + 3 * (f0 + 1) + 1] = fv[4];
        out[facesBase + 3 * (f0 + 1) + 2] = fv[5];
        out[uvIdxBase + 3 * f0 + 0] = (float)(4 * tet_idx);
        out[uvIdxBase + 3 * f0 + 1] = (float)(4 * tet_idx + 1);
        out[uvIdxBase + 3 * f0 + 2] = (float)(4 * tet_idx + 2);
        out[uvIdxBase + 3 * (f0 + 1) + 0] = (float)(4 * tet_idx);
        out[uvIdxBase + 3 * (f0 + 1) + 1] = (float)(4 * tet_idx + 2);
        out[uvIdxBase + 3 * (f0 + 1) + 2] = (float)(4 * tet_idx + 3);
    }
}

__global__ void k_uvs(float* out, const u64* meta0, const u32* NePtr, int Ngrid) {
    int c = blockIdx.x * 256 + threadIdx.x;
    int total = Ngrid * Ngrid;
    if (c >= total) return;
    u64 tot = *meta0;
    int C1 = (int)((tot >> 21) & 0x1fffffull);
    int C2 = (int)(tot & 0x1fffffull);
    int Ne = (int)*NePtr;
    long long uvBase = 3LL * Ne + 3LL * ((long long)C1 + 2LL * C2);
    int i = c / Ngrid, j = c % Ngrid;
    double step = (Ngrid > 1) ? (1.0 - 1.0 / (double)Ngrid) / (double)(Ngrid - 1) : 0.0;
    float x = (float)((double)j * step);
    float y = (float)((double)i * step);
    float pad = (float)(0.9 / (double)Ngrid);
    long long o = uvBase + 8LL * c;
    out[o + 0] = x;       out[o + 1] = y;
    out[o + 2] = x + pad; out[o + 3] = y;
    out[o + 4] = x + pad; out[o + 5] = y + pad;
    out[o + 6] = x;       out[o + 7] = y + pad;
}

// ---------------- host ----------------
template <typename T>
static void run_scan_t(const T* in, T* out, int n, T* blockSums, T* totalOut,
                       hipStream_t stream) {
    int nb = (n + SCAN_TILE - 1) / SCAN_TILE;
    scanA_t<T><<<nb, SCAN_BLOCK, 0, stream>>>(in, out, n, blockSums);
    scanB_t<T><<<1, 256, 0, stream>>>(blockSums, nb, totalOut);
    scanC_t<T><<<nb, SCAN_BLOCK, 0, stream>>>(out, n, blockSums);
}

extern "C" void kernel_launch(void* const* d_in, const int* in_sizes, int n_in,
                              void* d_out, int out_size, void* d_ws, size_t ws_size,
                              hipStream_t stream) {
    const float* pos = (const float*)d_in[0];
    const float* sdf = (const float*)d_in[1];
    const int* tet = (const int*)d_in[2];
    int V = in_sizes[1];
    int T = in_sizes[2] / 4;
    float* out = (float*)d_out;

    int NB = (V + BIN_VR - 1) / BIN_VR;

    char* p = (char*)d_ws;
    auto alloc = [&](size_t bytes) -> void* {
        void* r = (void*)p;
        p += (bytes + 255) & ~(size_t)255;
        return r;
    };
    u8*  ti8         = (u8*) alloc((size_t)T);
    u64* tetPack     = (u64*)alloc((size_t)T * 8);
    u64* tetScan     = (u64*)alloc((size_t)T * 8);
    u32* binCursor   = (u32*)alloc((size_t)NB * 4);
    u32* binData     = (u32*)alloc((size_t)NB * BIN_CAP * 4);
    u32* bucketCnt   = (u32*)alloc((size_t)V * 4);
    u32* padCnt      = (u32*)alloc((size_t)V * 4);
    u32* bucketStart = (u32*)alloc((size_t)V * 4);
    u32* crossCnt    = (u32*)alloc((size_t)V * 4);
    u32* crossScan   = (u32*)alloc((size_t)V * 4);
    uint2* meta2     = (uint2*)alloc((size_t)V * 8);
    u32* maxArr      = (u32*)alloc(((size_t)6 * T + 16 * (size_t)V) * 4);
    u64* blockSums64 = (u64*)alloc(2048 * 8);
    u32* blockSums32 = (u32*)alloc(2048 * 4);
    u64* meta64      = (u64*)alloc(8 * 8);
    u32* NePtr       = (u32*)(meta64 + 4);

    long long M = (2LL * T + 1) / 2;
    int Ngrid = (int)std::sqrt((double)M);
    while ((long long)Ngrid * Ngrid < M) ++Ngrid;
    if (Ngrid < 1) Ngrid = 1;
    long long uvFloats = 8LL * Ngrid * Ngrid;

    hipMemsetAsync(binCursor, 0, (size_t)NB * 4, stream);

    int gV = (V + 255) / 256;
    int gT = (T + 255) / 256;

    k_classify_bin<<<gT, 256, 0, stream>>>(tet, sdf, ti8, tetPack, binCursor, binData, T);
    run_scan_t<u64>(tetPack, tetScan, T, blockSums64, meta64, stream);
    k_bincount<<<NB, 256, 0, stream>>>(binCursor, binData, bucketCnt, V);
    k_pad<<<gV, 256, 0, stream>>>(bucketCnt, padCnt, V);
    run_scan_t<u32>(padCnt, bucketStart, V, blockSums32, nullptr, stream);
    k_binscatter<<<NB, 256, 0, stream>>>(binCursor, binData, bucketStart, maxArr, V);
    k_sortdedup<<<V, 64, 0, stream>>>(bucketCnt, bucketStart, maxArr, crossCnt, V);
    run_scan_t<u32>(crossCnt, crossScan, V, blockSums32, NePtr, stream);
    k_metapack<<<gV, 256, 0, stream>>>(bucketStart, crossCnt, crossScan, meta2, V);
    k_verts<<<V, 64, 0, stream>>>(crossCnt, bucketStart, maxArr, crossScan,
                                  pos, sdf, out, V);
    k_faces<<<gT, 256, 0, stream>>>(tet, ti8, tetScan, meta2, maxArr,
                                    meta64, NePtr, out, T, Ngrid, uvFloats);
    int gUV = (Ngrid * Ngrid + 255) / 256;
    k_uvs<<<gUV, 256, 0, stream>>>(out, meta64, NePtr, Ngrid);
}

// Round 7
// 579.196 us; speedup vs baseline: 4.3211x; 4.3211x over previous
//
#include <hip/hip_runtime.h>
#include <cmath>

typedef unsigned long long u64;
typedef unsigned int u32;
typedef unsigned char u8;

#define SCAN_BLOCK 256
#define SCAN_ELEMS 8
#define SCAN_TILE (SCAN_BLOCK * SCAN_ELEMS)

// counting-sort bins: 512 vertices per bin (V=200000 -> NB=391, LDS arrays 512)
// record packing (mn&511)<<18 | mx requires V <= 2^18.
#define BIN_SHIFT 9
#define BIN_VR 512
#define TETS_PER_BLOCK 2048

__constant__ int d_NUMTRI[16] = {0,1,1,2,1,2,2,1,1,2,2,1,2,1,1,0};
__constant__ int d_TRI[16][6] = {
 {-1,-1,-1,-1,-1,-1},{1,0,2,-1,-1,-1},{4,0,3,-1,-1,-1},{1,4,2,1,3,4},
 {3,1,5,-1,-1,-1},{2,3,0,2,5,3},{1,4,0,1,5,4},{4,2,5,-1,-1,-1},
 {4,5,2,-1,-1,-1},{4,1,0,4,5,1},{3,2,0,3,5,2},{1,3,5,-1,-1,-1},
 {4,1,2,4,3,1},{3,0,4,-1,-1,-1},{2,0,1,-1,-1,-1},{-1,-1,-1,-1,-1,-1}};
__constant__ int d_E0[6] = {0,0,0,1,1,2};
__constant__ int d_E1[6] = {1,2,3,2,3,3};

// ---------------- exclusive scan, templated element type ----------------
// NOTE: tet m1/m2 scan MUST be u64 — running m1 total needs 19 bits packed at
// bit 21 (overflowed u32 in round 3).
template <typename T>
__global__ void scanA_t(const T* in, T* out, int n, T* blockSums) {
    __shared__ T tsum[SCAN_BLOCK];
    int tbase = blockIdx.x * SCAN_TILE + threadIdx.x * SCAN_ELEMS;
    T vals[SCAN_ELEMS];
    T run = 0;
    for (int k = 0; k < SCAN_ELEMS; ++k) {
        int i = tbase + k;
        T v = (i < n) ? in[i] : (T)0;
        vals[k] = run;
        run += v;
    }
    tsum[threadIdx.x] = run;
    __syncthreads();
    for (int off = 1; off < SCAN_BLOCK; off <<= 1) {
        T v = (threadIdx.x >= (unsigned)off) ? tsum[threadIdx.x - off] : (T)0;
        __syncthreads();
        tsum[threadIdx.x] += v;
        __syncthreads();
    }
    T texcl = (threadIdx.x == 0) ? (T)0 : tsum[threadIdx.x - 1];
    for (int k = 0; k < SCAN_ELEMS; ++k) {
        int i = tbase + k;
        if (i < n) out[i] = texcl + vals[k];
    }
    if (threadIdx.x == SCAN_BLOCK - 1) blockSums[blockIdx.x] = tsum[SCAN_BLOCK - 1];
}

template <typename T>
__global__ void scanB_t(T* bs, int nb, T* totalOut) {
    __shared__ T sh[2048];
    for (int i = threadIdx.x; i < 2048; i += 256) sh[i] = (i < nb) ? bs[i] : (T)0;
    __syncthreads();
    for (int off = 1; off < 2048; off <<= 1) {
        T v[8];
        for (int k = 0; k < 8; ++k) {
            int i = threadIdx.x + k * 256;
            v[k] = (i >= off) ? sh[i - off] : (T)0;
        }
        __syncthreads();
        for (int k = 0; k < 8; ++k) sh[threadIdx.x + k * 256] += v[k];
        __syncthreads();
    }
    for (int i = threadIdx.x; i < nb; i += 256) bs[i] = (i == 0) ? (T)0 : sh[i - 1];
    if (threadIdx.x == 0 && totalOut) *totalOut = (nb > 0) ? sh[nb - 1] : (T)0;
}

template <typename T>
__global__ void scanC_t(T* out, int n, const T* bs) {
    int base = blockIdx.x * SCAN_TILE;
    T add = bs[blockIdx.x];
    int end = base + SCAN_TILE; if (end > n) end = n;
    for (int i = base + threadIdx.x; i < end; i += SCAN_BLOCK) out[i] += add;
}

// ---------------- pipeline ----------------
// Pass A: classify tets + per-block LDS histogram of crossing edges over bins.
// Zero global atomics.
__global__ __launch_bounds__(256) void k_classify_hist(
    const int* tet, const float* sdf, u8* ti8, u64* tetPack,
    u32* blockHist, int T, int NB, int gB) {
    __shared__ u32 hist[BIN_VR];
    for (int i = threadIdx.x; i < NB; i += 256) hist[i] = 0;
    __syncthreads();
    int base = blockIdx.x * TETS_PER_BLOCK;
    for (int it = 0; it < TETS_PER_BLOCK / 256; ++it) {
        int t = base + it * 256 + threadIdx.x;
        if (t < T) {
            int4 q = reinterpret_cast<const int4*>(tet)[t];
            int ti = (sdf[q.x] > 0.0f ? 1 : 0) | (sdf[q.y] > 0.0f ? 2 : 0) |
                     (sdf[q.z] > 0.0f ? 4 : 0) | (sdf[q.w] > 0.0f ? 8 : 0);
            ti8[t] = (u8)ti;
            int nt = d_NUMTRI[ti];
            tetPack[t] = ((u64)(nt == 1 ? 1 : 0) << 21) | (u64)(nt == 2 ? 1 : 0);
            if (nt != 0) {
                int idx[4] = {q.x, q.y, q.z, q.w};
                #pragma unroll
                for (int e = 0; e < 6; ++e) {
                    int e0 = d_E0[e], e1 = d_E1[e];
                    if (((ti >> e0) ^ (ti >> e1)) & 1) {
                        int a = idx[e0], b = idx[e1];
                        int mn = a < b ? a : b;
                        atomicAdd(&hist[mn >> BIN_SHIFT], 1u);
                    }
                }
            }
        }
    }
    __syncthreads();
    for (int i = threadIdx.x; i < NB; i += 256)
        blockHist[(size_t)i * gB + blockIdx.x] = hist[i];
}

// Pass B: re-walk the same tets; block-local LDS cursors (seeded from the
// scanned blockHist) hand out exact contiguous slots in the bin-sorted
// record array. Writes are block-local bursts -> writeback ~= payload.
__global__ __launch_bounds__(256) void k_binfill(
    const int* tet, const u8* ti8, const u32* blockHistScan,
    u32* binData, int T, int NB, int gB) {
    __shared__ u32 cur[BIN_VR];
    for (int i = threadIdx.x; i < NB; i += 256)
        cur[i] = blockHistScan[(size_t)i * gB + blockIdx.x];
    __syncthreads();
    int base = blockIdx.x * TETS_PER_BLOCK;
    for (int it = 0; it < TETS_PER_BLOCK / 256; ++it) {
        int t = base + it * 256 + threadIdx.x;
        if (t < T) {
            int ti = ti8[t];
            if (d_NUMTRI[ti] != 0) {
                int4 q = reinterpret_cast<const int4*>(tet)[t];
                int idx[4] = {q.x, q.y, q.z, q.w};
                #pragma unroll
                for (int e = 0; e < 6; ++e) {
                    int e0 = d_E0[e], e1 = d_E1[e];
                    if (((ti >> e0) ^ (ti >> e1)) & 1) {
                        int a = idx[e0], b = idx[e1];
                        int mn = a < b ? a : b;
                        int mx = a < b ? b : a;
                        u32 slot = atomicAdd(&cur[mn >> BIN_SHIFT], 1u);
                        binData[slot] = ((u32)(mn & (BIN_VR - 1)) << 18) | (u32)mx;
                    }
                }
            }
        }
    }
}

// one block per bin: LDS histogram over the bin's exact record range ->
// coalesced bucketCnt write (no global atomics)
__global__ __launch_bounds__(256) void k_bincount(
    const u32* blockHistScan, const u32* totalPtr, const u32* binData,
    u32* bucketCnt, int V, int NB, int gB) {
    int bin = blockIdx.x;
    __shared__ u32 hist[BIN_VR];
    for (int i = threadIdx.x; i < BIN_VR; i += 256) hist[i] = 0;
    __syncthreads();
    u32 s = blockHistScan[(size_t)bin * gB];
    u32 e = (bin + 1 < NB) ? blockHistScan[(size_t)(bin + 1) * gB] : *totalPtr;
    for (u32 i = s + threadIdx.x; i < e; i += 256)
        atomicAdd(&hist[binData[i] >> 18], 1u);
    __syncthreads();
    int vbase = bin << BIN_SHIFT;
    for (int i = threadIdx.x; i < BIN_VR; i += 256) {
        int v = vbase + i;
        if (v < V) bucketCnt[v] = hist[i];
    }
}

// round bucket counts up to 16 u32s => every bucket starts 64B-aligned
__global__ void k_pad(const u32* bucketCnt, u32* padCnt, int V) {
    int v = blockIdx.x * 256 + threadIdx.x;
    if (v < V) padCnt[v] = (bucketCnt[v] + 15u) & ~15u;
}

// one block per bin: LDS cursors (absolute bucketStart) -> scatter mx into
// maxArr. All writes land in the bin's ~50KB contiguous window -> L2-combined.
__global__ __launch_bounds__(256) void k_binscatter(
    const u32* blockHistScan, const u32* totalPtr, const u32* binData,
    const u32* bucketStart, u32* maxArr, int V, int NB, int gB) {
    int bin = blockIdx.x;
    __shared__ u32 cur[BIN_VR];
    int vbase = bin << BIN_SHIFT;
    for (int i = threadIdx.x; i < BIN_VR; i += 256) {
        int v = vbase + i;
        cur[i] = (v < V) ? bucketStart[v] : 0u;
    }
    __syncthreads();
    u32 s = blockHistScan[(size_t)bin * gB];
    u32 e = (bin + 1 < NB) ? blockHistScan[(size_t)(bin + 1) * gB] : *totalPtr;
    for (u32 i = s + threadIdx.x; i < e; i += 256) {
        u32 rec = binData[i];
        u32 slot = atomicAdd(&cur[rec >> 18], 1u);
        maxArr[slot] = rec & 0x3FFFFu;
    }
}

// one wave per bucket. n<=64: pure cross-lane (shfl rank + ds_permute scatter +
// ballot dedup), no LDS, no barriers. n<=256: LDS rank-sort. else serial.
__global__ __launch_bounds__(64) void k_sortdedup(
    const u32* bucketCnt, const u32* bucketStart, u32* maxArr, u32* crossCnt, int V)
{
    int v = blockIdx.x;
    if (v >= V) return;
    int lane = threadIdx.x;
    int n = (int)bucketCnt[v];
    if (n == 0) { if (lane == 0) crossCnt[v] = 0; return; }
    long long start = (long long)bucketStart[v];

    if (n <= 64) {
        u32 key = (lane < n) ? maxArr[start + lane] : 0xFFFFFFFFu;
        int rank = 0;
        #pragma unroll 16
        for (int j = 0; j < 64; ++j) {
            u32 kj = (u32)__shfl((int)key, j);
            rank += (kj < key || (kj == key && j < lane)) ? 1 : 0;
        }
        u32 sorted = (u32)__builtin_amdgcn_ds_permute(rank << 2, (int)key);
        u32 prev = (u32)__shfl((int)sorted, lane - 1);
        bool nf = (lane < n) && (lane == 0 || prev != sorted);
        u64 m = __ballot(nf);
        int idx = __popcll(m & ((1ull << lane) - 1ull));
        if (nf) maxArr[start + idx] = sorted;
        if (lane == 0) crossCnt[v] = (u32)__popcll(m);
    } else if (n <= 256) {
        __shared__ u32 sk[256];
        __shared__ u32 ss[256];
        int chunks = (n + 63) >> 6;
        u32 key[4];
        #pragma unroll
        for (int c = 0; c < 4; ++c) {
            if (c < chunks) {
                int i = (c << 6) + lane;
                key[c] = (i < n) ? maxArr[start + i] : 0xFFFFFFFFu;
                sk[(c << 6) + lane] = key[c];
            }
        }
        __syncthreads();
        int rank[4] = {0, 0, 0, 0};
        for (int j = 0; j < n; ++j) {
            u32 kj = sk[j];
            #pragma unroll
            for (int c = 0; c < 4; ++c) {
                if (c < chunks) {
                    int i = (c << 6) + lane;
                    rank[c] += (kj < key[c] || (kj == key[c] && j < i)) ? 1 : 0;
                }
            }
        }
        #pragma unroll
        for (int c = 0; c < 4; ++c) {
            if (c < chunks) { int i = (c << 6) + lane; if (i < n) ss[rank[c]] = key[c]; }
        }
        __syncthreads();
        int carryU = 0;
        for (int c = 0; c < chunks; ++c) {
            int i = (c << 6) + lane;
            bool valid = i < n;
            u32 k = ss[i < 256 ? i : 255];
            bool nf = valid && (i == 0 || ss[i - 1] != k);
            u64 mnf = __ballot(nf);
            u64 incl = (2ull << lane) - 1ull;
            int uIncl = carryU + __popcll(mnf & incl);
            if (nf) maxArr[start + uIncl - 1] = k;
            carryU += __popcll(mnf);
        }
        if (lane == 0) crossCnt[v] = (u32)carryU;
    } else if (lane == 0) {
        for (int i = 1; i < n; ++i) {
            u32 kk = maxArr[start + i];
            int j = i - 1;
            while (j >= 0 && maxArr[start + j] > kk) {
                maxArr[start + j + 1] = maxArr[start + j]; --j;
            }
            maxArr[start + j + 1] = kk;
        }
        int uc = 0; u32 prev = 0xFFFFFFFFu;
        for (int i = 0; i < n; ++i) {
            u32 k = maxArr[start + i];
            if (k != prev) { maxArr[start + uc] = k; ++uc; prev = k; }
        }
        crossCnt[v] = (u32)uc;
    }
}

// pack per-vertex lookup metadata: x=start, y=(u<<22)|crossScan  (1.6 MB total)
__global__ void k_metapack(const u32* bucketStart, const u32* crossCnt,
                           const u32* crossScan, uint2* meta2, int V) {
    int v = blockIdx.x * 256 + threadIdx.x;
    if (v < V) meta2[v] = make_uint2(bucketStart[v], (crossCnt[v] << 22) | crossScan[v]);
}

// one wave per bucket; lane i -> unique crossing edge i -> vertex crossScan[v]+i
__global__ __launch_bounds__(64) void k_verts(
    const u32* crossCnt, const u32* bucketStart, const u32* maxArr, const u32* crossScan,
    const float* pos, const float* sdf, float* out, int V)
{
    int v = blockIdx.x;
    if (v >= V) return;
    int lane = threadIdx.x;
    int u = (int)crossCnt[v];
    if (u == 0) return;
    long long start = (long long)bucketStart[v];
    int cBase = (int)crossScan[v];
    float s0 = sdf[v];
    float p0x = pos[3 * v], p0y = pos[3 * v + 1], p0z = pos[3 * v + 2];
    for (int i = lane; i < u; i += 64) {
        int b = (int)maxArr[start + i];
        long long k = cBase + i;
        float s1 = sdf[b];
        float d = s0 - s1;
        float w0 = -s1 / d, w1 = s0 / d;
        out[3 * k + 0] = p0x * w0 + pos[3 * b + 0] * w1;
        out[3 * k + 1] = p0y * w0 + pos[3 * b + 1] * w1;
        out[3 * k + 2] = p0z * w0 + pos[3 * b + 2] * w1;
    }
}

// faces + uv_idx; edge->vertex id via uint4 scan of 64B-aligned sorted bucket
__global__ void k_faces(const int* tet, const u8* ti8, const u64* tetScan,
                        const uint2* meta2, const u32* maxArr,
                        const u64* meta0, const u32* NePtr,
                        float* out, int T, int Ngrid, long long uvFloats)
{
    int t = blockIdx.x * 256 + threadIdx.x;
    if (t >= T) return;
    int ti = ti8[t];
    int nt = d_NUMTRI[ti];
    if (nt == 0) return;

    u64 tot = *meta0;
    int C1 = (int)((tot >> 21) & 0x1fffffull);
    int C2 = (int)(tot & 0x1fffffull);
    int Ne = (int)*NePtr;
    long long facesBase = 3LL * Ne;
    long long F = (long long)C1 + 2LL * C2;
    long long uvIdxBase = facesBase + 3LL * F + uvFloats;

    int4 q = reinterpret_cast<const int4*>(tet)[t];
    int idx[4] = {q.x, q.y, q.z, q.w};
    const int* row = d_TRI[ti];

    int emap[6];
    unsigned done = 0;
    float fv[6];
    #pragma unroll
    for (int j = 0; j < 6; ++j) {
        if (j >= 3 * nt) break;
        int e = row[j];
        if (!((done >> e) & 1)) {
            done |= 1u << e;
            int a = idx[d_E0[e]], b = idx[d_E1[e]];
            if (a > b) { int tmp = a; a = b; b = tmp; }
            uint2 m = meta2[a];
            int u = (int)(m.y >> 22);
            int base = (int)(m.y & 0x3FFFFFu);
            const uint4* bp = (const uint4*)(maxArr + m.x);  // 64B-aligned
            int cnt = 0;
            int nv = (u + 3) >> 2;
            for (int k4 = 0; k4 < nv; ++k4) {
                uint4 w = bp[k4];
                int b4 = k4 << 2;
                cnt += (b4 + 0 < u && (int)w.x < b) ? 1 : 0;
                cnt += (b4 + 1 < u && (int)w.y < b) ? 1 : 0;
                cnt += (b4 + 2 < u && (int)w.z < b) ? 1 : 0;
                cnt += (b4 + 3 < u && (int)w.w < b) ? 1 : 0;
            }
            emap[e] = base + cnt;
        }
        fv[j] = (float)emap[e];
    }

    u64 sc = tetScan[t];
    int r1 = (int)((sc >> 21) & 0x1fffffull);
    int r2 = (int)(sc & 0x1fffffull);
    int tet_idx = (t / Ngrid) * Ngrid + (t % Ngrid);

    if (nt == 1) {
        long long f = r1;
        out[facesBase + 3 * f + 0] = fv[0];
        out[facesBase + 3 * f + 1] = fv[1];
        out[facesBase + 3 * f + 2] = fv[2];
        out[uvIdxBase + 3 * f + 0] = (float)(4 * tet_idx);
        out[uvIdxBase + 3 * f + 1] = (float)(4 * tet_idx + 1);
        out[uvIdxBase + 3 * f + 2] = (float)(4 * tet_idx + 2);
    } else {
        long long f0 = (long long)C1 + 2LL * r2;
        out[facesBase + 3 * f0 + 0] = fv[0];
        out[facesBase + 3 * f0 + 1] = fv[1];
        out[facesBase + 3 * f0 + 2] = fv[2];
        out[facesBase + 3 * (f0 + 1) + 0] = fv[3];
        out[facesBase + 3 * (f0 + 1) + 1] = fv[4];
        out[facesBase + 3 * (f0 + 1) + 2] = fv[5];
        out[uvIdxBase + 3 * f0 + 0] = (float)(4 * tet_idx);
        out[uvIdxBase + 3 * f0 + 1] = (float)(4 * tet_idx + 1);
        out[uvIdxBase + 3 * f0 + 2] = (float)(4 * tet_idx + 2);
        out[uvIdxBase + 3 * (f0 + 1) + 0] = (float)(4 * tet_idx);
        out[uvIdxBase + 3 * (f0 + 1) + 1] = (float)(4 * tet_idx + 2);
        out[uvIdxBase + 3 * (f0 + 1) + 2] = (float)(4 * tet_idx + 3);
    }
}

__global__ void k_uvs(float* out, const u64* meta0, const u32* NePtr, int Ngrid) {
    int c = blockIdx.x * 256 + threadIdx.x;
    int total = Ngrid * Ngrid;
    if (c >= total) return;
    u64 tot = *meta0;
    int C1 = (int)((tot >> 21) & 0x1fffffull);
    int C2 = (int)(tot & 0x1fffffull);
    int Ne = (int)*NePtr;
    long long uvBase = 3LL * Ne + 3LL * ((long long)C1 + 2LL * C2);
    int i = c / Ngrid, j = c % Ngrid;
    double step = (Ngrid > 1) ? (1.0 - 1.0 / (double)Ngrid) / (double)(Ngrid - 1) : 0.0;
    float x = (float)((double)j * step);
    float y = (float)((double)i * step);
    float pad = (float)(0.9 / (double)Ngrid);
    long long o = uvBase + 8LL * c;
    out[o + 0] = x;       out[o + 1] = y;
    out[o + 2] = x + pad; out[o + 3] = y;
    out[o + 4] = x + pad; out[o + 5] = y + pad;
    out[o + 6] = x;       out[o + 7] = y + pad;
}

// ---------------- host ----------------
template <typename T>
static void run_scan_t(const T* in, T* out, int n, T* blockSums, T* totalOut,
                       hipStream_t stream) {
    int nb = (n + SCAN_TILE - 1) / SCAN_TILE;
    scanA_t<T><<<nb, SCAN_BLOCK, 0, stream>>>(in, out, n, blockSums);
    scanB_t<T><<<1, 256, 0, stream>>>(blockSums, nb, totalOut);
    scanC_t<T><<<nb, SCAN_BLOCK, 0, stream>>>(out, n, blockSums);
}

extern "C" void kernel_launch(void* const* d_in, const int* in_sizes, int n_in,
                              void* d_out, int out_size, void* d_ws, size_t ws_size,
                              hipStream_t stream) {
    const float* pos = (const float*)d_in[0];
    const float* sdf = (const float*)d_in[1];
    const int* tet = (const int*)d_in[2];
    int V = in_sizes[1];
    int T = in_sizes[2] / 4;
    float* out = (float*)d_out;

    int NB = (V + BIN_VR - 1) / BIN_VR;          // 391 bins (<=512 for V<=256K)
    int gB = (T + TETS_PER_BLOCK - 1) / TETS_PER_BLOCK;  // 489 fill blocks
    int nHist = NB * gB;

    char* p = (char*)d_ws;
    auto alloc = [&](size_t bytes) -> void* {
        void* r = (void*)p;
        p += (bytes + 255) & ~(size_t)255;
        return r;
    };
    u8*  ti8           = (u8*) alloc((size_t)T);
    u64* tetPack       = (u64*)alloc((size_t)T * 8);
    u64* tetScan       = (u64*)alloc((size_t)T * 8);
    u32* blockHist     = (u32*)alloc((size_t)nHist * 4);
    u32* blockHistScan = (u32*)alloc((size_t)nHist * 4);
    u32* binData       = (u32*)alloc((size_t)6 * T * 4);
    u32* bucketCnt     = (u32*)alloc((size_t)V * 4);
    u32* padCnt        = (u32*)alloc((size_t)V * 4);
    u32* bucketStart   = (u32*)alloc((size_t)V * 4);
    u32* crossCnt      = (u32*)alloc((size_t)V * 4);
    u32* crossScan     = (u32*)alloc((size_t)V * 4);
    uint2* meta2       = (uint2*)alloc((size_t)V * 8);
    u32* maxArr        = (u32*)alloc(((size_t)6 * T + 16 * (size_t)V) * 4);
    u64* blockSums64   = (u64*)alloc(2048 * 8);
    u32* blockSums32   = (u32*)alloc(2048 * 4);
    u64* meta64        = (u64*)alloc(8 * 8);
    u32* NePtr         = (u32*)(meta64 + 4);
    u32* NeInstPtr     = (u32*)(meta64 + 5);

    long long M = (2LL * T + 1) / 2;
    int Ngrid = (int)std::sqrt((double)M);
    while ((long long)Ngrid * Ngrid < M) ++Ngrid;
    if (Ngrid < 1) Ngrid = 1;
    long long uvFloats = 8LL * Ngrid * Ngrid;

    int gV = (V + 255) / 256;
    int gT = (T + 255) / 256;

    k_classify_hist<<<gB, 256, 0, stream>>>(tet, sdf, ti8, tetPack, blockHist,
                                            T, NB, gB);
    run_scan_t<u64>(tetPack, tetScan, T, blockSums64, meta64, stream);
    run_scan_t<u32>(blockHist, blockHistScan, nHist, blockSums32, NeInstPtr, stream);
    k_binfill<<<gB, 256, 0, stream>>>(tet, ti8, blockHistScan, binData, T, NB, gB);
    k_bincount<<<NB, 256, 0, stream>>>(blockHistScan, NeInstPtr, binData,
                                       bucketCnt, V, NB, gB);
    k_pad<<<gV, 256, 0, stream>>>(bucketCnt, padCnt, V);
    run_scan_t<u32>(padCnt, bucketStart, V, blockSums32, nullptr, stream);
    k_binscatter<<<NB, 256, 0, stream>>>(blockHistScan, NeInstPtr, binData,
                                         bucketStart, maxArr, V, NB, gB);
    k_sortdedup<<<V, 64, 0, stream>>>(bucketCnt, bucketStart, maxArr, crossCnt, V);
    run_scan_t<u32>(crossCnt, crossScan, V, blockSums32, NePtr, stream);
    k_metapack<<<gV, 256, 0, stream>>>(bucketStart, crossCnt, crossScan, meta2, V);
    k_verts<<<V, 64, 0, stream>>>(crossCnt, bucketStart, maxArr, crossScan,
                                  pos, sdf, out, V);
    k_faces<<<gT, 256, 0, stream>>>(tet, ti8, tetScan, meta2, maxArr,
                                    meta64, NePtr, out, T, Ngrid, uvFloats);
    int gUV = (Ngrid * Ngrid + 255) / 256;
    k_uvs<<<gUV, 256, 0, stream>>>(out, meta64, NePtr, Ngrid);
}

// Round 8
// 499.846 us; speedup vs baseline: 5.0071x; 1.1587x over previous
//
#include <hip/hip_runtime.h>
#include <cmath>

typedef unsigned long long u64;
typedef unsigned int u32;
typedef unsigned char u8;

#define SCAN_BLOCK 256
#define SCAN_ELEMS 8
#define SCAN_TILE (SCAN_BLOCK * SCAN_ELEMS)

// counting-sort bins: 512 vertices per bin (V=200000 -> NB=391, LDS arrays 512)
// record packing (mn&511)<<18 | mx requires V <= 2^18.
#define BIN_SHIFT 9
#define BIN_VR 512
#define TETS_PER_BLOCK 2048

__constant__ int d_NUMTRI[16] = {0,1,1,2,1,2,2,1,1,2,2,1,2,1,1,0};
__constant__ int d_TRI[16][6] = {
 {-1,-1,-1,-1,-1,-1},{1,0,2,-1,-1,-1},{4,0,3,-1,-1,-1},{1,4,2,1,3,4},
 {3,1,5,-1,-1,-1},{2,3,0,2,5,3},{1,4,0,1,5,4},{4,2,5,-1,-1,-1},
 {4,5,2,-1,-1,-1},{4,1,0,4,5,1},{3,2,0,3,5,2},{1,3,5,-1,-1,-1},
 {4,1,2,4,3,1},{3,0,4,-1,-1,-1},{2,0,1,-1,-1,-1},{-1,-1,-1,-1,-1,-1}};
__constant__ int d_E0[6] = {0,0,0,1,1,2};
__constant__ int d_E1[6] = {1,2,3,2,3,3};

// ---------------- exclusive scan, templated element type ----------------
// NOTE: tet m1/m2 scan MUST be u64 — running m1 total needs 19 bits packed at
// bit 21 (overflowed u32 in round 3).
template <typename T>
__global__ void scanA_t(const T* in, T* out, int n, T* blockSums) {
    __shared__ T tsum[SCAN_BLOCK];
    int tbase = blockIdx.x * SCAN_TILE + threadIdx.x * SCAN_ELEMS;
    T vals[SCAN_ELEMS];
    T run = 0;
    for (int k = 0; k < SCAN_ELEMS; ++k) {
        int i = tbase + k;
        T v = (i < n) ? in[i] : (T)0;
        vals[k] = run;
        run += v;
    }
    tsum[threadIdx.x] = run;
    __syncthreads();
    for (int off = 1; off < SCAN_BLOCK; off <<= 1) {
        T v = (threadIdx.x >= (unsigned)off) ? tsum[threadIdx.x - off] : (T)0;
        __syncthreads();
        tsum[threadIdx.x] += v;
        __syncthreads();
    }
    T texcl = (threadIdx.x == 0) ? (T)0 : tsum[threadIdx.x - 1];
    for (int k = 0; k < SCAN_ELEMS; ++k) {
        int i = tbase + k;
        if (i < n) out[i] = texcl + vals[k];
    }
    if (threadIdx.x == SCAN_BLOCK - 1) blockSums[blockIdx.x] = tsum[SCAN_BLOCK - 1];
}

template <typename T>
__global__ void scanB_t(T* bs, int nb, T* totalOut) {
    __shared__ T sh[2048];
    for (int i = threadIdx.x; i < 2048; i += 256) sh[i] = (i < nb) ? bs[i] : (T)0;
    __syncthreads();
    for (int off = 1; off < 2048; off <<= 1) {
        T v[8];
        for (int k = 0; k < 8; ++k) {
            int i = threadIdx.x + k * 256;
            v[k] = (i >= off) ? sh[i - off] : (T)0;
        }
        __syncthreads();
        for (int k = 0; k < 8; ++k) sh[threadIdx.x + k * 256] += v[k];
        __syncthreads();
    }
    for (int i = threadIdx.x; i < nb; i += 256) bs[i] = (i == 0) ? (T)0 : sh[i - 1];
    if (threadIdx.x == 0 && totalOut) *totalOut = (nb > 0) ? sh[nb - 1] : (T)0;
}

template <typename T>
__global__ void scanC_t(T* out, int n, const T* bs) {
    int base = blockIdx.x * SCAN_TILE;
    T add = bs[blockIdx.x];
    int end = base + SCAN_TILE; if (end > n) end = n;
    for (int i = base + threadIdx.x; i < end; i += SCAN_BLOCK) out[i] += add;
}

// ---------------- pipeline ----------------
// Pass A: classify tets + per-block LDS histogram of crossing edges over bins.
__global__ __launch_bounds__(256) void k_classify_hist(
    const int* tet, const float* sdf, u8* ti8, u64* tetPack,
    u32* blockHist, int T, int NB, int gB) {
    __shared__ u32 hist[BIN_VR];
    for (int i = threadIdx.x; i < NB; i += 256) hist[i] = 0;
    __syncthreads();
    int base = blockIdx.x * TETS_PER_BLOCK;
    for (int it = 0; it < TETS_PER_BLOCK / 256; ++it) {
        int t = base + it * 256 + threadIdx.x;
        if (t < T) {
            int4 q = reinterpret_cast<const int4*>(tet)[t];
            int ti = (sdf[q.x] > 0.0f ? 1 : 0) | (sdf[q.y] > 0.0f ? 2 : 0) |
                     (sdf[q.z] > 0.0f ? 4 : 0) | (sdf[q.w] > 0.0f ? 8 : 0);
            ti8[t] = (u8)ti;
            int nt = d_NUMTRI[ti];
            tetPack[t] = ((u64)(nt == 1 ? 1 : 0) << 21) | (u64)(nt == 2 ? 1 : 0);
            if (nt != 0) {
                int idx[4] = {q.x, q.y, q.z, q.w};
                #pragma unroll
                for (int e = 0; e < 6; ++e) {
                    int e0 = d_E0[e], e1 = d_E1[e];
                    if (((ti >> e0) ^ (ti >> e1)) & 1) {
                        int a = idx[e0], b = idx[e1];
                        int mn = a < b ? a : b;
                        atomicAdd(&hist[mn >> BIN_SHIFT], 1u);
                    }
                }
            }
        }
    }
    __syncthreads();
    for (int i = threadIdx.x; i < NB; i += 256)
        blockHist[(size_t)i * gB + blockIdx.x] = hist[i];
}

// Pass B: block-local LDS cursors hand out exact contiguous slots in the
// bin-sorted record array. Writes are block-local bursts.
__global__ __launch_bounds__(256) void k_binfill(
    const int* tet, const u8* ti8, const u32* blockHistScan,
    u32* binData, int T, int NB, int gB) {
    __shared__ u32 cur[BIN_VR];
    for (int i = threadIdx.x; i < NB; i += 256)
        cur[i] = blockHistScan[(size_t)i * gB + blockIdx.x];
    __syncthreads();
    int base = blockIdx.x * TETS_PER_BLOCK;
    for (int it = 0; it < TETS_PER_BLOCK / 256; ++it) {
        int t = base + it * 256 + threadIdx.x;
        if (t < T) {
            int ti = ti8[t];
            if (d_NUMTRI[ti] != 0) {
                int4 q = reinterpret_cast<const int4*>(tet)[t];
                int idx[4] = {q.x, q.y, q.z, q.w};
                #pragma unroll
                for (int e = 0; e < 6; ++e) {
                    int e0 = d_E0[e], e1 = d_E1[e];
                    if (((ti >> e0) ^ (ti >> e1)) & 1) {
                        int a = idx[e0], b = idx[e1];
                        int mn = a < b ? a : b;
                        int mx = a < b ? b : a;
                        u32 slot = atomicAdd(&cur[mn >> BIN_SHIFT], 1u);
                        binData[slot] = ((u32)(mn & (BIN_VR - 1)) << 18) | (u32)mx;
                    }
                }
            }
        }
    }
}

// one block per bin: LDS histogram over the bin's record range -> coalesced
// bucketCnt AND 16-rounded padCnt writes (pad kernel fused away)
__global__ __launch_bounds__(256) void k_bincount(
    const u32* blockHistScan, const u32* totalPtr, const u32* binData,
    u32* bucketCnt, u32* padCnt, int V, int NB, int gB) {
    int bin = blockIdx.x;
    __shared__ u32 hist[BIN_VR];
    for (int i = threadIdx.x; i < BIN_VR; i += 256) hist[i] = 0;
    __syncthreads();
    u32 s = blockHistScan[(size_t)bin * gB];
    u32 e = (bin + 1 < NB) ? blockHistScan[(size_t)(bin + 1) * gB] : *totalPtr;
    for (u32 i = s + threadIdx.x; i < e; i += 256)
        atomicAdd(&hist[binData[i] >> 18], 1u);
    __syncthreads();
    int vbase = bin << BIN_SHIFT;
    for (int i = threadIdx.x; i < BIN_VR; i += 256) {
        int v = vbase + i;
        if (v < V) {
            u32 h = hist[i];
            bucketCnt[v] = h;
            padCnt[v] = (h + 15u) & ~15u;
        }
    }
}

// one block per bin: LDS cursors (absolute bucketStart) -> scatter mx into
// maxArr. All writes land in the bin's contiguous window -> L2-combined.
__global__ __launch_bounds__(256) void k_binscatter(
    const u32* blockHistScan, const u32* totalPtr, const u32* binData,
    const u32* bucketStart, u32* maxArr, int V, int NB, int gB) {
    int bin = blockIdx.x;
    __shared__ u32 cur[BIN_VR];
    int vbase = bin << BIN_SHIFT;
    for (int i = threadIdx.x; i < BIN_VR; i += 256) {
        int v = vbase + i;
        cur[i] = (v < V) ? bucketStart[v] : 0u;
    }
    __syncthreads();
    u32 s = blockHistScan[(size_t)bin * gB];
    u32 e = (bin + 1 < NB) ? blockHistScan[(size_t)(bin + 1) * gB] : *totalPtr;
    for (u32 i = s + threadIdx.x; i < e; i += 256) {
        u32 rec = binData[i];
        u32 slot = atomicAdd(&cur[rec >> 18], 1u);
        maxArr[slot] = rec & 0x3FFFFu;
    }
}

// one wave per bucket. n<=64: cross-lane rank sort with DYNAMIC loop bound
// (n is wave-uniform; pad lanes get rank==n — harmless, only lanes<n consumed).
__global__ __launch_bounds__(64) void k_sortdedup(
    const u32* bucketCnt, const u32* bucketStart, u32* maxArr, u32* crossCnt, int V)
{
    int v = blockIdx.x;
    if (v >= V) return;
    int lane = threadIdx.x;
    int n = (int)bucketCnt[v];
    if (n == 0) { if (lane == 0) crossCnt[v] = 0; return; }
    long long start = (long long)bucketStart[v];

    if (n <= 64) {
        u32 key = (lane < n) ? maxArr[start + lane] : 0xFFFFFFFFu;
        int rank = 0;
        for (int j = 0; j < n; ++j) {           // dynamic bound: avg n~15, was 64
            u32 kj = (u32)__shfl((int)key, j);
            rank += (kj < key || (kj == key && j < lane)) ? 1 : 0;
        }
        u32 sorted = (u32)__builtin_amdgcn_ds_permute(rank << 2, (int)key);
        u32 prev = (u32)__shfl((int)sorted, lane - 1);
        bool nf = (lane < n) && (lane == 0 || prev != sorted);
        u64 m = __ballot(nf);
        int idx = __popcll(m & ((1ull << lane) - 1ull));
        if (nf) maxArr[start + idx] = sorted;
        if (lane == 0) crossCnt[v] = (u32)__popcll(m);
    } else if (n <= 256) {
        __shared__ u32 sk[256];
        __shared__ u32 ss[256];
        int chunks = (n + 63) >> 6;
        u32 key[4];
        #pragma unroll
        for (int c = 0; c < 4; ++c) {
            if (c < chunks) {
                int i = (c << 6) + lane;
                key[c] = (i < n) ? maxArr[start + i] : 0xFFFFFFFFu;
                sk[(c << 6) + lane] = key[c];
            }
        }
        __syncthreads();
        int rank[4] = {0, 0, 0, 0};
        for (int j = 0; j < n; ++j) {
            u32 kj = sk[j];
            #pragma unroll
            for (int c = 0; c < 4; ++c) {
                if (c < chunks) {
                    int i = (c << 6) + lane;
                    rank[c] += (kj < key[c] || (kj == key[c] && j < i)) ? 1 : 0;
                }
            }
        }
        #pragma unroll
        for (int c = 0; c < 4; ++c) {
            if (c < chunks) { int i = (c << 6) + lane; if (i < n) ss[rank[c]] = key[c]; }
        }
        __syncthreads();
        int carryU = 0;
        for (int c = 0; c < chunks; ++c) {
            int i = (c << 6) + lane;
            bool valid = i < n;
            u32 k = ss[i < 256 ? i : 255];
            bool nf = valid && (i == 0 || ss[i - 1] != k);
            u64 mnf = __ballot(nf);
            u64 incl = (2ull << lane) - 1ull;
            int uIncl = carryU + __popcll(mnf & incl);
            if (nf) maxArr[start + uIncl - 1] = k;
            carryU += __popcll(mnf);
        }
        if (lane == 0) crossCnt[v] = (u32)carryU;
    } else if (lane == 0) {
        for (int i = 1; i < n; ++i) {
            u32 kk = maxArr[start + i];
            int j = i - 1;
            while (j >= 0 && maxArr[start + j] > kk) {
                maxArr[start + j + 1] = maxArr[start + j]; --j;
            }
            maxArr[start + j + 1] = kk;
        }
        int uc = 0; u32 prev = 0xFFFFFFFFu;
        for (int i = 0; i < n; ++i) {
            u32 k = maxArr[start + i];
            if (k != prev) { maxArr[start + uc] = k; ++uc; prev = k; }
        }
        crossCnt[v] = (u32)uc;
    }
}

// pack per-vertex lookup metadata: x=start, y=(u<<22)|crossScan  (1.6 MB total)
__global__ void k_metapack(const u32* bucketStart, const u32* crossCnt,
                           const u32* crossScan, uint2* meta2, int V) {
    int v = blockIdx.x * 256 + threadIdx.x;
    if (v < V) meta2[v] = make_uint2(bucketStart[v], (crossCnt[v] << 22) | crossScan[v]);
}

// one wave per bucket; lane i -> unique crossing edge i -> vertex crossScan[v]+i
__global__ __launch_bounds__(64) void k_verts(
    const u32* crossCnt, const u32* bucketStart, const u32* maxArr, const u32* crossScan,
    const float* pos, const float* sdf, float* out, int V)
{
    int v = blockIdx.x;
    if (v >= V) return;
    int lane = threadIdx.x;
    int u = (int)crossCnt[v];
    if (u == 0) return;
    long long start = (long long)bucketStart[v];
    int cBase = (int)crossScan[v];
    float s0 = sdf[v];
    float p0x = pos[3 * v], p0y = pos[3 * v + 1], p0z = pos[3 * v + 2];
    for (int i = lane; i < u; i += 64) {
        int b = (int)maxArr[start + i];
        long long k = cBase + i;
        float s1 = sdf[b];
        float d = s0 - s1;
        float w0 = -s1 / d, w1 = s0 / d;
        out[3 * k + 0] = p0x * w0 + pos[3 * b + 0] * w1;
        out[3 * k + 1] = p0y * w0 + pos[3 * b + 1] * w1;
        out[3 * k + 2] = p0z * w0 + pos[3 * b + 2] * w1;
    }
}

// faces + uv_idx; edge->vertex id via uint4 scan of 64B-aligned sorted bucket
__global__ void k_faces(const int* tet, const u8* ti8, const u64* tetScan,
                        const uint2* meta2, const u32* maxArr,
                        const u64* meta0, const u32* NePtr,
                        float* out, int T, int Ngrid, long long uvFloats)
{
    int t = blockIdx.x * 256 + threadIdx.x;
    if (t >= T) return;
    int ti = ti8[t];
    int nt = d_NUMTRI[ti];
    if (nt == 0) return;

    u64 tot = *meta0;
    int C1 = (int)((tot >> 21) & 0x1fffffull);
    int C2 = (int)(tot & 0x1fffffull);
    int Ne = (int)*NePtr;
    long long facesBase = 3LL * Ne;
    long long F = (long long)C1 + 2LL * C2;
    long long uvIdxBase = facesBase + 3LL * F + uvFloats;

    int4 q = reinterpret_cast<const int4*>(tet)[t];
    int idx[4] = {q.x, q.y, q.z, q.w};
    const int* row = d_TRI[ti];

    int emap[6];
    unsigned done = 0;
    float fv[6];
    #pragma unroll
    for (int j = 0; j < 6; ++j) {
        if (j >= 3 * nt) break;
        int e = row[j];
        if (!((done >> e) & 1)) {
            done |= 1u << e;
            int a = idx[d_E0[e]], b = idx[d_E1[e]];
            if (a > b) { int tmp = a; a = b; b = tmp; }
            uint2 m = meta2[a];
            int u = (int)(m.y >> 22);
            int base = (int)(m.y & 0x3FFFFFu);
            const uint4* bp = (const uint4*)(maxArr + m.x);  // 64B-aligned
            int cnt = 0;
            int nv = (u + 3) >> 2;
            for (int k4 = 0; k4 < nv; ++k4) {
                uint4 w = bp[k4];
                int b4 = k4 << 2;
                cnt += (b4 + 0 < u && (int)w.x < b) ? 1 : 0;
                cnt += (b4 + 1 < u && (int)w.y < b) ? 1 : 0;
                cnt += (b4 + 2 < u && (int)w.z < b) ? 1 : 0;
                cnt += (b4 + 3 < u && (int)w.w < b) ? 1 : 0;
            }
            emap[e] = base + cnt;
        }
        fv[j] = (float)emap[e];
    }

    u64 sc = tetScan[t];
    int r1 = (int)((sc >> 21) & 0x1fffffull);
    int r2 = (int)(sc & 0x1fffffull);
    int tet_idx = (t / Ngrid) * Ngrid + (t % Ngrid);

    if (nt == 1) {
        long long f = r1;
        out[facesBase + 3 * f + 0] = fv[0];
        out[facesBase + 3 * f + 1] = fv[1];
        out[facesBase + 3 * f + 2] = fv[2];
        out[uvIdxBase + 3 * f + 0] = (float)(4 * tet_idx);
        out[uvIdxBase + 3 * f + 1] = (float)(4 * tet_idx + 1);
        out[uvIdxBase + 3 * f + 2] = (float)(4 * tet_idx + 2);
    } else {
        long long f0 = (long long)C1 + 2LL * r2;
        out[facesBase + 3 * f0 + 0] = fv[0];
        out[facesBase + 3 * f0 + 1] = fv[1];
        out[facesBase + 3 * f0 + 2] = fv[2];
        out[facesBase + 3 * (f0 + 1) + 0] = fv[3];
        out[facesBase + 3 * (f0 + 1) + 1] = fv[4];
        out[facesBase + 3 * (f0 + 1) + 2] = fv[5];
        out[uvIdxBase + 3 * f0 + 0] = (float)(4 * tet_idx);
        out[uvIdxBase + 3 * f0 + 1] = (float)(4 * tet_idx + 1);
        out[uvIdxBase + 3 * f0 + 2] = (float)(4 * tet_idx + 2);
        out[uvIdxBase + 3 * (f0 + 1) + 0] = (float)(4 * tet_idx);
        out[uvIdxBase + 3 * (f0 + 1) + 1] = (float)(4 * tet_idx + 2);
        out[uvIdxBase + 3 * (f0 + 1) + 2] = (float)(4 * tet_idx + 3);
    }
}

__global__ void k_uvs(float* out, const u64* meta0, const u32* NePtr, int Ngrid) {
    int c = blockIdx.x * 256 + threadIdx.x;
    int total = Ngrid * Ngrid;
    if (c >= total) return;
    u64 tot = *meta0;
    int C1 = (int)((tot >> 21) & 0x1fffffull);
    int C2 = (int)(tot & 0x1fffffull);
    int Ne = (int)*NePtr;
    long long uvBase = 3LL * Ne + 3LL * ((long long)C1 + 2LL * C2);
    int i = c / Ngrid, j = c % Ngrid;
    double step = (Ngrid > 1) ? (1.0 - 1.0 / (double)Ngrid) / (double)(Ngrid - 1) : 0.0;
    float x = (float)((double)j * step);
    float y = (float)((double)i * step);
    float pad = (float)(0.9 / (double)Ngrid);
    long long o = uvBase + 8LL * c;
    out[o + 0] = x;       out[o + 1] = y;
    out[o + 2] = x + pad; out[o + 3] = y;
    out[o + 4] = x + pad; out[o + 5] = y + pad;
    out[o + 6] = x;       out[o + 7] = y + pad;
}

// ---------------- host ----------------
template <typename T>
static void run_scan_t(const T* in, T* out, int n, T* blockSums, T* totalOut,
                       hipStream_t stream) {
    int nb = (n + SCAN_TILE - 1) / SCAN_TILE;
    scanA_t<T><<<nb, SCAN_BLOCK, 0, stream>>>(in, out, n, blockSums);
    scanB_t<T><<<1, 256, 0, stream>>>(blockSums, nb, totalOut);
    scanC_t<T><<<nb, SCAN_BLOCK, 0, stream>>>(out, n, blockSums);
}

extern "C" void kernel_launch(void* const* d_in, const int* in_sizes, int n_in,
                              void* d_out, int out_size, void* d_ws, size_t ws_size,
                              hipStream_t stream) {
    const float* pos = (const float*)d_in[0];
    const float* sdf = (const float*)d_in[1];
    const int* tet = (const int*)d_in[2];
    int V = in_sizes[1];
    int T = in_sizes[2] / 4;
    float* out = (float*)d_out;

    int NB = (V + BIN_VR - 1) / BIN_VR;
    int gB = (T + TETS_PER_BLOCK - 1) / TETS_PER_BLOCK;
    int nHist = NB * gB;

    char* p = (char*)d_ws;
    auto alloc = [&](size_t bytes) -> void* {
        void* r = (void*)p;
        p += (bytes + 255) & ~(size_t)255;
        return r;
    };
    u8*  ti8           = (u8*) alloc((size_t)T);
    u64* tetPack       = (u64*)alloc((size_t)T * 8);
    u64* tetScan       = (u64*)alloc((size_t)T * 8);
    u32* blockHist     = (u32*)alloc((size_t)nHist * 4);
    u32* blockHistScan = (u32*)alloc((size_t)nHist * 4);
    u32* binData       = (u32*)alloc((size_t)6 * T * 4);
    u32* bucketCnt     = (u32*)alloc((size_t)V * 4);
    u32* padCnt        = (u32*)alloc((size_t)V * 4);
    u32* bucketStart   = (u32*)alloc((size_t)V * 4);
    u32* crossCnt      = (u32*)alloc((size_t)V * 4);
    u32* crossScan     = (u32*)alloc((size_t)V * 4);
    uint2* meta2       = (uint2*)alloc((size_t)V * 8);
    u32* maxArr        = (u32*)alloc(((size_t)6 * T + 16 * (size_t)V) * 4);
    u64* blockSums64   = (u64*)alloc(2048 * 8);
    u32* blockSums32   = (u32*)alloc(2048 * 4);
    u64* meta64        = (u64*)alloc(8 * 8);
    u32* NePtr         = (u32*)(meta64 + 4);
    u32* NeInstPtr     = (u32*)(meta64 + 5);

    long long M = (2LL * T + 1) / 2;
    int Ngrid = (int)std::sqrt((double)M);
    while ((long long)Ngrid * Ngrid < M) ++Ngrid;
    if (Ngrid < 1) Ngrid = 1;
    long long uvFloats = 8LL * Ngrid * Ngrid;

    int gV = (V + 255) / 256;
    int gT = (T + 255) / 256;

    k_classify_hist<<<gB, 256, 0, stream>>>(tet, sdf, ti8, tetPack, blockHist,
                                            T, NB, gB);
    run_scan_t<u64>(tetPack, tetScan, T, blockSums64, meta64, stream);
    run_scan_t<u32>(blockHist, blockHistScan, nHist, blockSums32, NeInstPtr, stream);
    k_binfill<<<gB, 256, 0, stream>>>(tet, ti8, blockHistScan, binData, T, NB, gB);
    k_bincount<<<NB, 256, 0, stream>>>(blockHistScan, NeInstPtr, binData,
                                       bucketCnt, padCnt, V, NB, gB);
    run_scan_t<u32>(padCnt, bucketStart, V, blockSums32, nullptr, stream);
    k_binscatter<<<NB, 256, 0, stream>>>(blockHistScan, NeInstPtr, binData,
                                         bucketStart, maxArr, V, NB, gB);
    k_sortdedup<<<V, 64, 0, stream>>>(bucketCnt, bucketStart, maxArr, crossCnt, V);
    run_scan_t<u32>(crossCnt, crossScan, V, blockSums32, NePtr, stream);
    k_metapack<<<gV, 256, 0, stream>>>(bucketStart, crossCnt, crossScan, meta2, V);
    k_verts<<<V, 64, 0, stream>>>(crossCnt, bucketStart, maxArr, crossScan,
                                  pos, sdf, out, V);
    k_faces<<<gT, 256, 0, stream>>>(tet, ti8, tetScan, meta2, maxArr,
                                    meta64, NePtr, out, T, Ngrid, uvFloats);
    int gUV = (Ngrid * Ngrid + 255) / 256;
    k_uvs<<<gUV, 256, 0, stream>>>(out, meta64, NePtr, Ngrid);
}